// Round 1
// baseline (1680.578 us; speedup 1.0000x reference)
//
#include <hip/hip_runtime.h>
#include <cstdint>
#include <cstddef>

// ---------------------------------------------------------------------------
// ResidualAttentionBlock_adapter — MI355X (gfx950)
// Strategy: fp32 residual stream in d_out; all GEMMs in bf16 MFMA
// (16x16x32), m97-style 128x128 tile with global_load_lds(16B).
// Attention fused per (bt,head): scores in regs (17 x f32x4), K from
// global (L1-resident), V^T + per-wave P tiles in LDS (<64KB static).
// ---------------------------------------------------------------------------

typedef unsigned short u16;
typedef __attribute__((ext_vector_type(4))) float  f32x4;
typedef __attribute__((ext_vector_type(8))) short  bf16x8;
typedef __attribute__((ext_vector_type(4))) unsigned int u32x4;

#define AS1 __attribute__((address_space(1)))
#define AS3 __attribute__((address_space(3)))

__device__ __forceinline__ float bf2f(u16 u) {
  unsigned int x = ((unsigned int)u) << 16;
  return __builtin_bit_cast(float, x);
}
__device__ __forceinline__ u16 f2bf(float f) {
  unsigned int x = __builtin_bit_cast(unsigned int, f);
  x = x + 0x7fffu + ((x >> 16) & 1u);   // round-to-nearest-even
  return (u16)(x >> 16);
}
__device__ __forceinline__ unsigned int pack2(float a, float b) {
  return (unsigned int)f2bf(a) | ((unsigned int)f2bf(b) << 16);
}

// async global->LDS, 16B per lane. LDS dest is wave-uniform base + lane*16.
__device__ __forceinline__ void gload_lds16(const void* g, void* l) {
  __builtin_amdgcn_global_load_lds((const AS1 unsigned int*)g,
                                   (AS3 unsigned int*)l, 16, 0, 0);
}

// ---------------------------------------------------------------------------
// Weight fp32 -> bf16 conversion (all 8 matrices in one kernel).
// Cumulative element offsets (each segment % 4 == 0):
//   w_in 0, w_out 3145728, o_fc1 4194304, o_fc2 4587520, a_fc1 4980736,
//   a_fc2 5373952, mlp_fc 5767168, mlp_proj 9961472, end 14155776
// ---------------------------------------------------------------------------
__global__ __launch_bounds__(256) void cvt_weights(
    const float* __restrict__ w_in, const float* __restrict__ w_out,
    const float* __restrict__ ofc1, const float* __restrict__ ofc2,
    const float* __restrict__ afc1, const float* __restrict__ afc2,
    const float* __restrict__ mfc,  const float* __restrict__ mproj,
    u16* __restrict__ dst)
{
  long i4 = (long)blockIdx.x * 256 + threadIdx.x;   // 3,538,944 float4 units
  long e = i4 * 4;
  const float* src; long base;
  if      (e < 3145728L) { src = w_in;  base = 0L; }
  else if (e < 4194304L) { src = w_out; base = 3145728L; }
  else if (e < 4587520L) { src = ofc1;  base = 4194304L; }
  else if (e < 4980736L) { src = ofc2;  base = 4587520L; }
  else if (e < 5373952L) { src = afc1;  base = 4980736L; }
  else if (e < 5767168L) { src = afc2;  base = 5373952L; }
  else if (e < 9961472L) { src = mfc;   base = 5767168L; }
  else                   { src = mproj; base = 9961472L; }
  float4 v = *(const float4*)(src + (e - base));
  uint2 o; o.x = pack2(v.x, v.y); o.y = pack2(v.z, v.w);
  *(uint2*)(dst + e) = o;
}

// ---------------------------------------------------------------------------
// Fused LayerNorm (D=1024) -> bf16.  One block (256 thr) per row.
// ---------------------------------------------------------------------------
__global__ __launch_bounds__(256) void ln_bf16(
    const float* __restrict__ x, const float* __restrict__ g,
    const float* __restrict__ b, u16* __restrict__ out)
{
  int row = blockIdx.x;
  const float4* xr = (const float4*)(x + (size_t)row * 1024);
  float4 v = xr[threadIdx.x];
  float s = v.x + v.y + v.z + v.w;
  float q = v.x * v.x + v.y * v.y + v.z * v.z + v.w * v.w;
  #pragma unroll
  for (int m = 1; m < 64; m <<= 1) { s += __shfl_xor(s, m); q += __shfl_xor(q, m); }
  __shared__ float ss[4], qq[4];
  if ((threadIdx.x & 63) == 0) { ss[threadIdx.x >> 6] = s; qq[threadIdx.x >> 6] = q; }
  __syncthreads();
  s = ss[0] + ss[1] + ss[2] + ss[3];
  q = qq[0] + qq[1] + qq[2] + qq[3];
  float mu = s * (1.f / 1024.f);
  float var = q * (1.f / 1024.f) - mu * mu;
  float rs = rsqrtf(var + 1e-5f);
  float4 gg = ((const float4*)g)[threadIdx.x];
  float4 bb = ((const float4*)b)[threadIdx.x];
  float o0 = (v.x - mu) * rs * gg.x + bb.x;
  float o1 = (v.y - mu) * rs * gg.y + bb.y;
  float o2 = (v.z - mu) * rs * gg.z + bb.z;
  float o3 = (v.w - mu) * rs * gg.w + bb.w;
  uint2 o; o.x = pack2(o0, o1); o.y = pack2(o2, o3);
  *(uint2*)(out + (size_t)row * 1024 + threadIdx.x * 4) = o;
}

// ---------------------------------------------------------------------------
// Temporal diff (offset adapter front): diff[f, p, :] = x1[f, p+1tok] -
// x1[f_prev, p+1tok]  (f = bv*16+t, f_prev = f-1 unless t==0 -> f) -> bf16
// 16384 rows x 1024.  One float4 per thread.
// ---------------------------------------------------------------------------
__global__ __launch_bounds__(256) void diff_bf16(
    const float* __restrict__ x1, u16* __restrict__ out)
{
  int i = blockIdx.x * 256 + threadIdx.x;   // 4,194,304 units
  int r = i >> 8;                           // 0..16383
  int c4 = i & 255;
  int f = r >> 8;                           // frame 0..63
  int p = r & 255;
  int t = f & 15;
  int rowA = f * 257 + 1 + p;
  int rowB = (t == 0) ? rowA : (f - 1) * 257 + 1 + p;
  float4 a = ((const float4*)(x1 + (size_t)rowA * 1024))[c4];
  float4 b = ((const float4*)(x1 + (size_t)rowB * 1024))[c4];
  uint2 o; o.x = pack2(a.x - b.x, a.y - b.y); o.y = pack2(a.z - b.z, a.w - b.w);
  *(uint2*)(out + (size_t)r * 1024 + c4 * 4) = o;
}

// ---------------------------------------------------------------------------
// Depthwise 3x3 spatial conv (per frame, zero pad).  in/out: [64][16][16][384]
// ---------------------------------------------------------------------------
__global__ __launch_bounds__(256) void dwconv3x3(
    const u16* __restrict__ in, const float* __restrict__ w,
    const float* __restrict__ bias, u16* __restrict__ out)
{
  int idx = blockIdx.x * 256 + threadIdx.x;  // 6,291,456
  int c = idx % 384;
  int pos = idx / 384;
  int xx = pos & 15, yy = (pos >> 4) & 15, f = pos >> 8;
  float acc = bias[c];
  #pragma unroll
  for (int kh = 0; kh < 3; kh++) {
    int y2 = yy + kh - 1;
    if (y2 < 0 || y2 > 15) continue;
    #pragma unroll
    for (int kw = 0; kw < 3; kw++) {
      int x2 = xx + kw - 1;
      if (x2 < 0 || x2 > 15) continue;
      acc += bf2f(in[((size_t)(f * 256 + y2 * 16 + x2)) * 384 + c]) * w[(kh * 3 + kw) * 384 + c];
    }
  }
  out[(size_t)idx] = f2bf(acc);
}

// ---------------------------------------------------------------------------
// Depthwise temporal conv1d (kernel 3, zero pad).  in/out: [64*257][384]
// rows ordered (bv,t,l); neighbors are t +- 1.
// ---------------------------------------------------------------------------
__global__ __launch_bounds__(256) void dwconv1d(
    const u16* __restrict__ in, const float* __restrict__ w,
    const float* __restrict__ bias, u16* __restrict__ out)
{
  int idx = blockIdx.x * 256 + threadIdx.x;  // 6,316,032
  int c = idx % 384;
  int rl = idx / 384;
  int bt = rl / 257, l = rl % 257;
  int bv = bt >> 4, t = bt & 15;
  float acc = bias[c];
  #pragma unroll
  for (int dt = 0; dt < 3; dt++) {
    int tt = t + dt - 1;
    if (tt < 0 || tt > 15) continue;
    acc += bf2f(in[((size_t)((bv * 16 + tt) * 257 + l)) * 384 + c]) * w[dt * 384 + c];
  }
  out[(size_t)idx] = f2bf(acc);
}

// ---------------------------------------------------------------------------
// bf16 GEMM, C = A(MxK) @ B(NxK)^T + bias, m97 structure:
// 128x128 tile, BK=64, 4 waves (2x2), global_load_lds 16B, 16x16x32 MFMA.
// Epilogues templated.
// ---------------------------------------------------------------------------
enum { EPI_BF16 = 0, EPI_GELU = 1, EPI_RES = 2, EPI_ACC = 3, EPI_ACC_SKIPCLS = 4 };

template <int EPI>
__global__ __launch_bounds__(256) void gemm_bt(
    const u16* __restrict__ A, const u16* __restrict__ B,
    const float* __restrict__ bias,
    float* __restrict__ outF, u16* __restrict__ outB,
    const float* __restrict__ resid,
    int M, int N, int K)
{
  __shared__ u16 As[128 * 64];
  __shared__ u16 Bs[128 * 64];
  const int t = threadIdx.x, l = t & 63, w = t >> 6;
  const int row0 = blockIdx.x * 128, col0 = blockIdx.y * 128;
  const int wr = w >> 1, wc = w & 1;
  const int lo = l & 15, hi = l >> 4;
  const int larow = l >> 3, lacol = (l & 7) * 8;

  f32x4 acc[4][4];
  const f32x4 z = {0.f, 0.f, 0.f, 0.f};
  #pragma unroll
  for (int m = 0; m < 4; m++)
    #pragma unroll
    for (int n = 0; n < 4; n++) acc[m][n] = z;

  for (int k0 = 0; k0 < K; k0 += 64) {
    #pragma unroll
    for (int i = 0; i < 4; i++) {
      int rr = i * 32 + w * 8 + larow;
      int ra = row0 + rr; ra = (ra < M) ? ra : (M - 1);       // clamp tail rows
      gload_lds16(A + (size_t)ra * K + k0 + lacol, As + i * 2048 + w * 512);
      gload_lds16(B + (size_t)(col0 + rr) * K + k0 + lacol, Bs + i * 2048 + w * 512);
    }
    __syncthreads();
    #pragma unroll
    for (int kk = 0; kk < 2; kk++) {
      bf16x8 af[4], bfr[4];
      #pragma unroll
      for (int m = 0; m < 4; m++)
        af[m] = __builtin_bit_cast(bf16x8,
          *(const u32x4*)&As[(wr * 64 + m * 16 + lo) * 64 + kk * 32 + hi * 8]);
      #pragma unroll
      for (int n = 0; n < 4; n++)
        bfr[n] = __builtin_bit_cast(bf16x8,
          *(const u32x4*)&Bs[(wc * 64 + n * 16 + lo) * 64 + kk * 32 + hi * 8]);
      #pragma unroll
      for (int m = 0; m < 4; m++)
        #pragma unroll
        for (int n = 0; n < 4; n++)
          acc[m][n] = __builtin_amdgcn_mfma_f32_16x16x32_bf16(af[m], bfr[n], acc[m][n], 0, 0, 0);
    }
    __syncthreads();
  }

  const int rbase = row0 + wr * 64, cbase = col0 + wc * 64;
  #pragma unroll
  for (int n = 0; n < 4; n++) {
    int colc = cbase + n * 16 + lo;
    float bv = bias[colc];
    #pragma unroll
    for (int m = 0; m < 4; m++) {
      int rr0 = rbase + m * 16 + hi * 4;
      #pragma unroll
      for (int j = 0; j < 4; j++) {
        int r = rr0 + j;
        if (r >= M) continue;
        float v = acc[m][n][j] + bv;
        if constexpr (EPI == EPI_BF16) {
          outB[(size_t)r * N + colc] = f2bf(v);
        } else if constexpr (EPI == EPI_GELU) {
          float gv = v / (1.f + __expf(-1.702f * v));   // QuickGELU
          outB[(size_t)r * N + colc] = f2bf(gv);
        } else if constexpr (EPI == EPI_RES) {
          float sres = resid[(size_t)r * N + colc] + v;
          outF[(size_t)r * N + colc] = sres;            // fp32 residual stream
          outB[(size_t)r * N + colc] = f2bf(sres);      // bf16 copy for adapter GEMMs
        } else if constexpr (EPI == EPI_ACC) {
          outF[(size_t)r * N + colc] += v;
        } else { // EPI_ACC_SKIPCLS: row r=(frame*256+p) -> d_out row frame*257+1+p
          int rm = (r >> 8) * 257 + (r & 255) + 1;
          outF[(size_t)rm * N + colc] += v;
        }
      }
    }
  }
}

// ---------------------------------------------------------------------------
// Fused attention.  Block = (bt, head), 4 waves, each wave owns q-chunks of
// 16 rows (chunk c in {w, w+4, ...} over 17 chunks; 272 >= 257 rows).
// K read directly from global (33KB/block, L1/L2-resident).  V^T in LDS.
// P staged per-wave in LDS in 3 phases (128/128/32 keys) to fit 64KB.
// qkv layout: [16448][3072] bf16, q|k|v each 1024 wide, head h at h*64.
// ---------------------------------------------------------------------------
__global__ __launch_bounds__(256) void attn_kernel(
    const u16* __restrict__ qkv, u16* __restrict__ out)
{
  __shared__ u16 Vt[64 * 296];       // V transposed: [d][key], keys 257..295 zeroed
  __shared__ u16 Ps[4][16 * 136];    // per-wave P tile, 3-phase (128-key slabs)
  const int bt = blockIdx.x >> 4;
  const int h  = blockIdx.x & 15;
  const int t  = threadIdx.x, l = t & 63, w = t >> 6;
  const int lo = l & 15, hi = l >> 4;
  const size_t base = (size_t)bt * 257 * 3072 + (size_t)h * 64;

  // stage V transposed
  for (int ch = t; ch < 257 * 8; ch += 256) {
    int r = ch >> 3, s8 = ch & 7;
    u32x4 v = *(const u32x4*)(qkv + base + (size_t)r * 3072 + 2048 + s8 * 8);
    union { u32x4 v4; u16 us[8]; } cv; cv.v4 = v;
    #pragma unroll
    for (int i = 0; i < 8; i++) Vt[(s8 * 8 + i) * 296 + r] = cv.us[i];
  }
  // zero pad keys 257..295 (NaN-safe PV)
  for (int ch = t; ch < 64 * 39; ch += 256)
    Vt[(ch / 39) * 296 + 257 + (ch % 39)] = 0;
  __syncthreads();

  for (int c = w; c < 17; c += 4) {
    int qr = c * 16 + lo; qr = (qr < 257) ? qr : 256;
    const u16* qp = qkv + base + (size_t)qr * 3072 + hi * 8;
    bf16x8 q0 = __builtin_bit_cast(bf16x8, *(const u32x4*)qp);
    bf16x8 q1 = __builtin_bit_cast(bf16x8, *(const u32x4*)(qp + 32));

    // scores: 17 key tiles of 16, K-dim = 64 (2 MFMA each)
    f32x4 s[17];
    #pragma unroll
    for (int tt = 0; tt < 17; tt++) {
      int kr = tt * 16 + lo; kr = (kr < 257) ? kr : 256;
      const u16* kp = qkv + base + (size_t)kr * 3072 + 1024 + hi * 8;
      bf16x8 k0 = __builtin_bit_cast(bf16x8, *(const u32x4*)kp);
      bf16x8 k1 = __builtin_bit_cast(bf16x8, *(const u32x4*)(kp + 32));
      f32x4 a = {0.f, 0.f, 0.f, 0.f};
      a = __builtin_amdgcn_mfma_f32_16x16x32_bf16(q0, k0, a, 0, 0, 0);
      a = __builtin_amdgcn_mfma_f32_16x16x32_bf16(q1, k1, a, 0, 0, 0);
      s[tt] = a;
    }
    // scale + mask + row softmax (row = hi*4+j, cols spread over lanes lo)
    float mx[4] = {-1e30f, -1e30f, -1e30f, -1e30f};
    #pragma unroll
    for (int tt = 0; tt < 17; tt++) {
      int key = tt * 16 + lo;
      #pragma unroll
      for (int j = 0; j < 4; j++) {
        float v = s[tt][j] * 0.125f;          // hd^-0.5, exact
        v = (key < 257) ? v : -1e30f;
        s[tt][j] = v;
        mx[j] = fmaxf(mx[j], v);
      }
    }
    #pragma unroll
    for (int j = 0; j < 4; j++)
      #pragma unroll
      for (int msk = 1; msk < 16; msk <<= 1) mx[j] = fmaxf(mx[j], __shfl_xor(mx[j], msk));
    float sm[4] = {0.f, 0.f, 0.f, 0.f};
    #pragma unroll
    for (int tt = 0; tt < 17; tt++)
      #pragma unroll
      for (int j = 0; j < 4; j++) {
        float p = __expf(s[tt][j] - mx[j]);
        s[tt][j] = p; sm[j] += p;
      }
    #pragma unroll
    for (int j = 0; j < 4; j++) {
      #pragma unroll
      for (int msk = 1; msk < 16; msk <<= 1) sm[j] += __shfl_xor(sm[j], msk);
      sm[j] = 1.f / sm[j];
    }

    // PV in 3 phases of 128/128/32 keys through the per-wave P tile
    u16* P = &Ps[w][0];
    f32x4 o[4];
    #pragma unroll
    for (int n = 0; n < 4; n++) o[n] = (f32x4){0.f, 0.f, 0.f, 0.f};
    #pragma unroll
    for (int ph = 0; ph < 3; ph++) {
      const int TT = (ph < 2) ? 8 : 1;
      #pragma unroll
      for (int ti = 0; ti < TT; ti++) {
        int tt = ph * 8 + ti;
        #pragma unroll
        for (int j = 0; j < 4; j++)
          P[(hi * 4 + j) * 136 + ti * 16 + lo] = f2bf(s[tt][j] * sm[j]);
      }
      if (ph == 2) {
        #pragma unroll
        for (int j = 0; j < 4; j++) P[(hi * 4 + j) * 136 + 16 + lo] = 0;
      }
      const int NKS = (ph < 2) ? 4 : 1;
      #pragma unroll
      for (int ks = 0; ks < NKS; ks++) {
        bf16x8 af = __builtin_bit_cast(bf16x8,
          *(const u32x4*)&P[lo * 136 + ks * 32 + hi * 8]);
        #pragma unroll
        for (int n = 0; n < 4; n++) {
          bf16x8 bfr = __builtin_bit_cast(bf16x8,
            *(const u32x4*)&Vt[(n * 16 + lo) * 296 + ph * 128 + ks * 32 + hi * 8]);
          o[n] = __builtin_amdgcn_mfma_f32_16x16x32_bf16(af, bfr, o[n], 0, 0, 0);
        }
      }
    }
    // store out rows (guard tail rows of chunk 16)
    #pragma unroll
    for (int n = 0; n < 4; n++)
      #pragma unroll
      for (int j = 0; j < 4; j++) {
        int row = c * 16 + hi * 4 + j;
        if (row < 257)
          out[(size_t)(bt * 257 + row) * 1024 + h * 64 + n * 16 + lo] = f2bf(o[n][j]);
      }
  }
}

// ---------------------------------------------------------------------------
// launch
// ---------------------------------------------------------------------------
extern "C" void kernel_launch(void* const* d_in, const int* in_sizes, int n_in,
                              void* d_out, int out_size, void* d_ws, size_t ws_size,
                              hipStream_t stream)
{
  const float* x       = (const float*)d_in[0];
  const float* ln1_g   = (const float*)d_in[1];
  const float* ln1_b   = (const float*)d_in[2];
  const float* w_in    = (const float*)d_in[3];
  const float* b_in    = (const float*)d_in[4];
  const float* w_out   = (const float*)d_in[5];
  const float* b_out   = (const float*)d_in[6];
  const float* o_fc1_w = (const float*)d_in[7];
  const float* o_fc1_b = (const float*)d_in[8];
  const float* o_conv_w= (const float*)d_in[9];
  const float* o_conv_b= (const float*)d_in[10];
  const float* o_fc2_w = (const float*)d_in[11];
  const float* o_fc2_b = (const float*)d_in[12];
  const float* a_fc1_w = (const float*)d_in[13];
  const float* a_fc1_b = (const float*)d_in[14];
  const float* a_conv_w= (const float*)d_in[15];
  const float* a_conv_b= (const float*)d_in[16];
  const float* a_fc2_w = (const float*)d_in[17];
  const float* a_fc2_b = (const float*)d_in[18];
  const float* ln2_g   = (const float*)d_in[19];
  const float* ln2_b   = (const float*)d_in[20];
  const float* mfc_w   = (const float*)d_in[21];
  const float* mfc_b   = (const float*)d_in[22];
  const float* mproj_w = (const float*)d_in[23];
  const float* mproj_b = (const float*)d_in[24];
  float* xo = (float*)d_out;   // fp32 residual stream lives here

  // workspace layout (bytes)
  char* ws = (char*)d_ws;
  u16* WB = (u16*)ws;                                 // 14,155,776 bf16 weights
  u16* R0 = (u16*)(ws + 28311552);                    // 16448x1024 bf16
  u16* R1 = (u16*)(ws + 28311552 + 33685504);         // 16448x3072 bf16 (qkv)
  u16* R2 = (u16*)(ws + 28311552 + 33685504 + 101056512); // 16448x1024 bf16
  // bf16 weight sub-pointers
  u16* w_in_bf  = WB + 0;
  u16* w_out_bf = WB + 3145728;
  u16* ofc1_bf  = WB + 4194304;
  u16* ofc2_bf  = WB + 4587520;
  u16* afc1_bf  = WB + 4980736;
  u16* afc2_bf  = WB + 5373952;
  u16* mfc_bf   = WB + 5767168;
  u16* mproj_bf = WB + 9961472;
  // adapter scratch inside R1 (free after attention consumes qkv)
  u16* off1 = R1;                       // 16384x384
  u16* offc = R1 + 6291456;             // 16384x384
  u16* y1   = R1 + 12582912;            // 16448x384
  u16* yc   = R1 + 12582912 + 6316032;  // 16448x384

  // 1) weights -> bf16
  cvt_weights<<<13824, 256, 0, stream>>>(w_in, w_out, o_fc1_w, o_fc2_w,
                                         a_fc1_w, a_fc2_w, mfc_w, mproj_w, WB);
  // 2) LN1 -> bf16
  ln_bf16<<<16448, 256, 0, stream>>>(x, ln1_g, ln1_b, R0);
  // 3) qkv = ln1 @ w_in^T + b_in  (bf16)
  gemm_bt<EPI_BF16><<<dim3(129, 24), 256, 0, stream>>>(
      R0, w_in_bf, b_in, nullptr, R1, nullptr, 16448, 3072, 1024);
  // 4) attention -> R2 (bf16)
  attn_kernel<<<1024, 256, 0, stream>>>(R1, R2);
  // 5) x1 = x + att @ w_out^T + b_out  -> d_out (fp32) + R0 (bf16)
  gemm_bt<EPI_RES><<<dim3(129, 8), 256, 0, stream>>>(
      R2, w_out_bf, b_out, xo, R0, x, 16448, 1024, 1024);
  // 6) temporal diff -> R2 (bf16, 16384x1024)
  diff_bf16<<<16384, 256, 0, stream>>>(xo, R2);
  // 7) off1 = diff @ o_fc1^T + b
  gemm_bt<EPI_BF16><<<dim3(128, 3), 256, 0, stream>>>(
      R2, ofc1_bf, o_fc1_b, nullptr, off1, nullptr, 16384, 384, 1024);
  // 8) depthwise 3x3
  dwconv3x3<<<24576, 256, 0, stream>>>(off1, o_conv_w, o_conv_b, offc);
  // 9) d_out[:,1:,:] += offc @ o_fc2^T + b
  gemm_bt<EPI_ACC_SKIPCLS><<<dim3(128, 8), 256, 0, stream>>>(
      offc, ofc2_bf, o_fc2_b, xo, nullptr, nullptr, 16384, 1024, 384);
  // 10) y1 = x1 @ a_fc1^T + b
  gemm_bt<EPI_BF16><<<dim3(129, 3), 256, 0, stream>>>(
      R0, afc1_bf, a_fc1_b, nullptr, y1, nullptr, 16448, 384, 1024);
  // 11) temporal depthwise conv1d
  dwconv1d<<<24672, 256, 0, stream>>>(y1, a_conv_w, a_conv_b, yc);
  // 12) d_out += yc @ a_fc2^T + b
  gemm_bt<EPI_ACC><<<dim3(129, 8), 256, 0, stream>>>(
      yc, afc2_bf, a_fc2_b, xo, nullptr, nullptr, 16448, 1024, 384);
  // 13) LN2 -> bf16
  ln_bf16<<<16448, 256, 0, stream>>>(xo, ln2_g, ln2_b, R0);
  // 14) h = QuickGELU(ln2 @ mlp_fc^T + b) -> R1 (16448x4096 spans R1+R2)
  gemm_bt<EPI_GELU><<<dim3(129, 32), 256, 0, stream>>>(
      R0, mfc_bf, mfc_b, nullptr, R1, nullptr, 16448, 4096, 1024);
  // 15) d_out += h @ mlp_proj^T + b
  gemm_bt<EPI_ACC><<<dim3(129, 8), 256, 0, stream>>>(
      R1, mproj_bf, mproj_b, xo, nullptr, nullptr, 16448, 1024, 4096);
}

// Round 2
// 1483.478 us; speedup vs baseline: 1.1329x; 1.1329x over previous
//
#include <hip/hip_runtime.h>
#include <cstdint>
#include <cstddef>

// ---------------------------------------------------------------------------
// ResidualAttentionBlock_adapter — MI355X (gfx950)  — round 2
// Big GEMMs: 256x256 tile, BK=32, 8 waves, 3-buffer 2-deep counted-vmcnt
// pipeline (never vmcnt(0) in steady state), T2 XOR-swizzled LDS
// (inverse-swizzled global_load_lds source + swizzled ds_read), bijective
// XCD blockIdx swizzle.  Small-N GEMMs keep the m97 128x128 kernel.
// ---------------------------------------------------------------------------

typedef unsigned short u16;
typedef __attribute__((ext_vector_type(4))) float  f32x4;
typedef __attribute__((ext_vector_type(8))) short  bf16x8;
typedef __attribute__((ext_vector_type(4))) unsigned int u32x4;

#define AS1 __attribute__((address_space(1)))
#define AS3 __attribute__((address_space(3)))

__device__ __forceinline__ float bf2f(u16 u) {
  unsigned int x = ((unsigned int)u) << 16;
  return __builtin_bit_cast(float, x);
}
__device__ __forceinline__ u16 f2bf(float f) {
  unsigned int x = __builtin_bit_cast(unsigned int, f);
  x = x + 0x7fffu + ((x >> 16) & 1u);   // round-to-nearest-even
  return (u16)(x >> 16);
}
__device__ __forceinline__ unsigned int pack2(float a, float b) {
  return (unsigned int)f2bf(a) | ((unsigned int)f2bf(b) << 16);
}
__device__ __forceinline__ int imin(int a, int b) { return a < b ? a : b; }

// async global->LDS, 16B per lane. LDS dest is wave-uniform base + lane*16.
__device__ __forceinline__ void gload_lds16(const void* g, void* l) {
  __builtin_amdgcn_global_load_lds((const AS1 unsigned int*)g,
                                   (AS3 unsigned int*)l, 16, 0, 0);
}

// ---------------------------------------------------------------------------
// Weight fp32 -> bf16 conversion (all 8 matrices in one kernel).
// ---------------------------------------------------------------------------
__global__ __launch_bounds__(256) void cvt_weights(
    const float* __restrict__ w_in, const float* __restrict__ w_out,
    const float* __restrict__ ofc1, const float* __restrict__ ofc2,
    const float* __restrict__ afc1, const float* __restrict__ afc2,
    const float* __restrict__ mfc,  const float* __restrict__ mproj,
    u16* __restrict__ dst)
{
  long i4 = (long)blockIdx.x * 256 + threadIdx.x;   // 3,538,944 float4 units
  long e = i4 * 4;
  const float* src; long base;
  if      (e < 3145728L) { src = w_in;  base = 0L; }
  else if (e < 4194304L) { src = w_out; base = 3145728L; }
  else if (e < 4587520L) { src = ofc1;  base = 4194304L; }
  else if (e < 4980736L) { src = ofc2;  base = 4587520L; }
  else if (e < 5373952L) { src = afc1;  base = 4980736L; }
  else if (e < 5767168L) { src = afc2;  base = 5373952L; }
  else if (e < 9961472L) { src = mfc;   base = 5767168L; }
  else                   { src = mproj; base = 9961472L; }
  float4 v = *(const float4*)(src + (e - base));
  uint2 o; o.x = pack2(v.x, v.y); o.y = pack2(v.z, v.w);
  *(uint2*)(dst + e) = o;
}

// ---------------------------------------------------------------------------
// Fused LayerNorm (D=1024) -> bf16.  One block (256 thr) per row.
// ---------------------------------------------------------------------------
__global__ __launch_bounds__(256) void ln_bf16(
    const float* __restrict__ x, const float* __restrict__ g,
    const float* __restrict__ b, u16* __restrict__ out)
{
  int row = blockIdx.x;
  const float4* xr = (const float4*)(x + (size_t)row * 1024);
  float4 v = xr[threadIdx.x];
  float s = v.x + v.y + v.z + v.w;
  float q = v.x * v.x + v.y * v.y + v.z * v.z + v.w * v.w;
  #pragma unroll
  for (int m = 1; m < 64; m <<= 1) { s += __shfl_xor(s, m); q += __shfl_xor(q, m); }
  __shared__ float ss[4], qq[4];
  if ((threadIdx.x & 63) == 0) { ss[threadIdx.x >> 6] = s; qq[threadIdx.x >> 6] = q; }
  __syncthreads();
  s = ss[0] + ss[1] + ss[2] + ss[3];
  q = qq[0] + qq[1] + qq[2] + qq[3];
  float mu = s * (1.f / 1024.f);
  float var = q * (1.f / 1024.f) - mu * mu;
  float rs = rsqrtf(var + 1e-5f);
  float4 gg = ((const float4*)g)[threadIdx.x];
  float4 bb = ((const float4*)b)[threadIdx.x];
  float o0 = (v.x - mu) * rs * gg.x + bb.x;
  float o1 = (v.y - mu) * rs * gg.y + bb.y;
  float o2 = (v.z - mu) * rs * gg.z + bb.z;
  float o3 = (v.w - mu) * rs * gg.w + bb.w;
  uint2 o; o.x = pack2(o0, o1); o.y = pack2(o2, o3);
  *(uint2*)(out + (size_t)row * 1024 + threadIdx.x * 4) = o;
}

// ---------------------------------------------------------------------------
// Temporal diff -> bf16, 16384 rows x 1024.
// ---------------------------------------------------------------------------
__global__ __launch_bounds__(256) void diff_bf16(
    const float* __restrict__ x1, u16* __restrict__ out)
{
  int i = blockIdx.x * 256 + threadIdx.x;   // 4,194,304 units
  int r = i >> 8;                           // 0..16383
  int c4 = i & 255;
  int f = r >> 8;                           // frame 0..63
  int p = r & 255;
  int t = f & 15;
  int rowA = f * 257 + 1 + p;
  int rowB = (t == 0) ? rowA : (f - 1) * 257 + 1 + p;
  float4 a = ((const float4*)(x1 + (size_t)rowA * 1024))[c4];
  float4 b = ((const float4*)(x1 + (size_t)rowB * 1024))[c4];
  uint2 o; o.x = pack2(a.x - b.x, a.y - b.y); o.y = pack2(a.z - b.z, a.w - b.w);
  *(uint2*)(out + (size_t)r * 1024 + c4 * 4) = o;
}

// ---------------------------------------------------------------------------
// Depthwise 3x3 spatial conv (per frame, zero pad).  [64][16][16][384]
// ---------------------------------------------------------------------------
__global__ __launch_bounds__(256) void dwconv3x3(
    const u16* __restrict__ in, const float* __restrict__ w,
    const float* __restrict__ bias, u16* __restrict__ out)
{
  int idx = blockIdx.x * 256 + threadIdx.x;  // 6,291,456
  int c = idx % 384;
  int pos = idx / 384;
  int xx = pos & 15, yy = (pos >> 4) & 15, f = pos >> 8;
  float acc = bias[c];
  #pragma unroll
  for (int kh = 0; kh < 3; kh++) {
    int y2 = yy + kh - 1;
    if (y2 < 0 || y2 > 15) continue;
    #pragma unroll
    for (int kw = 0; kw < 3; kw++) {
      int x2 = xx + kw - 1;
      if (x2 < 0 || x2 > 15) continue;
      acc += bf2f(in[((size_t)(f * 256 + y2 * 16 + x2)) * 384 + c]) * w[(kh * 3 + kw) * 384 + c];
    }
  }
  out[(size_t)idx] = f2bf(acc);
}

// ---------------------------------------------------------------------------
// Depthwise temporal conv1d (kernel 3, zero pad).  [64*257][384]
// ---------------------------------------------------------------------------
__global__ __launch_bounds__(256) void dwconv1d(
    const u16* __restrict__ in, const float* __restrict__ w,
    const float* __restrict__ bias, u16* __restrict__ out)
{
  int idx = blockIdx.x * 256 + threadIdx.x;  // 6,316,032
  int c = idx % 384;
  int rl = idx / 384;
  int bt = rl / 257, l = rl % 257;
  int bv = bt >> 4, t = bt & 15;
  float acc = bias[c];
  #pragma unroll
  for (int dt = 0; dt < 3; dt++) {
    int tt = t + dt - 1;
    if (tt < 0 || tt > 15) continue;
    acc += bf2f(in[((size_t)((bv * 16 + tt) * 257 + l)) * 384 + c]) * w[dt * 384 + c];
  }
  out[(size_t)idx] = f2bf(acc);
}

enum { EPI_BF16 = 0, EPI_GELU = 1, EPI_RES = 2, EPI_ACC = 3, EPI_ACC_SKIPCLS = 4 };

// ---------------------------------------------------------------------------
// 128x128 m97-style GEMM (kept for N=384 GEMMs).
// ---------------------------------------------------------------------------
template <int EPI>
__global__ __launch_bounds__(256) void gemm_bt(
    const u16* __restrict__ A, const u16* __restrict__ B,
    const float* __restrict__ bias,
    float* __restrict__ outF, u16* __restrict__ outB,
    const float* __restrict__ resid,
    int M, int N, int K)
{
  __shared__ u16 As[128 * 64];
  __shared__ u16 Bs[128 * 64];
  const int t = threadIdx.x, l = t & 63, w = t >> 6;
  const int row0 = blockIdx.x * 128, col0 = blockIdx.y * 128;
  const int wr = w >> 1, wc = w & 1;
  const int lo = l & 15, hi = l >> 4;
  const int larow = l >> 3, lacol = (l & 7) * 8;

  f32x4 acc[4][4];
  const f32x4 z = {0.f, 0.f, 0.f, 0.f};
  #pragma unroll
  for (int m = 0; m < 4; m++)
    #pragma unroll
    for (int n = 0; n < 4; n++) acc[m][n] = z;

  for (int k0 = 0; k0 < K; k0 += 64) {
    #pragma unroll
    for (int i = 0; i < 4; i++) {
      int rr = i * 32 + w * 8 + larow;
      int ra = row0 + rr; ra = (ra < M) ? ra : (M - 1);
      gload_lds16(A + (size_t)ra * K + k0 + lacol, As + i * 2048 + w * 512);
      gload_lds16(B + (size_t)(col0 + rr) * K + k0 + lacol, Bs + i * 2048 + w * 512);
    }
    __syncthreads();
    #pragma unroll
    for (int kk = 0; kk < 2; kk++) {
      bf16x8 af[4], bfr[4];
      #pragma unroll
      for (int m = 0; m < 4; m++)
        af[m] = __builtin_bit_cast(bf16x8,
          *(const u32x4*)&As[(wr * 64 + m * 16 + lo) * 64 + kk * 32 + hi * 8]);
      #pragma unroll
      for (int n = 0; n < 4; n++)
        bfr[n] = __builtin_bit_cast(bf16x8,
          *(const u32x4*)&Bs[(wc * 64 + n * 16 + lo) * 64 + kk * 32 + hi * 8]);
      #pragma unroll
      for (int m = 0; m < 4; m++)
        #pragma unroll
        for (int n = 0; n < 4; n++)
          acc[m][n] = __builtin_amdgcn_mfma_f32_16x16x32_bf16(af[m], bfr[n], acc[m][n], 0, 0, 0);
    }
    __syncthreads();
  }

  const int rbase = row0 + wr * 64, cbase = col0 + wc * 64;
  #pragma unroll
  for (int n = 0; n < 4; n++) {
    int colc = cbase + n * 16 + lo;
    float bv = bias[colc];
    #pragma unroll
    for (int m = 0; m < 4; m++) {
      int rr0 = rbase + m * 16 + hi * 4;
      #pragma unroll
      for (int j = 0; j < 4; j++) {
        int r = rr0 + j;
        if (r >= M) continue;
        float v = acc[m][n][j] + bv;
        if constexpr (EPI == EPI_BF16) {
          outB[(size_t)r * N + colc] = f2bf(v);
        } else if constexpr (EPI == EPI_GELU) {
          float gv = v / (1.f + __expf(-1.702f * v));
          outB[(size_t)r * N + colc] = f2bf(gv);
        } else if constexpr (EPI == EPI_RES) {
          float sres = resid[(size_t)r * N + colc] + v;
          outF[(size_t)r * N + colc] = sres;
          outB[(size_t)r * N + colc] = f2bf(sres);
        } else if constexpr (EPI == EPI_ACC) {
          outF[(size_t)r * N + colc] += v;
        } else {
          int rm = (r >> 8) * 257 + (r & 255) + 1;
          outF[(size_t)rm * N + colc] += v;
        }
      }
    }
  }
}

// ---------------------------------------------------------------------------
// 256x256 GEMM, BK=32, 8 waves (2x4), 3-buffer 2-deep counted-vmcnt pipeline,
// XOR-swizzled LDS (inverse-swizzled gload source + swizzled ds_read).
// LDS: A 3x16KB + B 3x16KB = 96KB.  C = A(MxK) @ B(NxK)^T + bias.
// Requires: K%32==0, K>=64, N%256==0.
// ---------------------------------------------------------------------------
template <int EPI>
__global__ __launch_bounds__(512, 2) void gemm256(
    const u16* __restrict__ A, const u16* __restrict__ B,
    const float* __restrict__ bias,
    float* __restrict__ outF, u16* __restrict__ outB,
    const float* __restrict__ resid,
    int M, int N, int K, int gm)
{
  __shared__ u16 lds[49152];                 // 96 KB
  const int tid = threadIdx.x;
  const int w = tid >> 6, lane = tid & 63;
  const int lo = lane & 15, hi = lane >> 4;
  const int wm = w >> 2, wn = w & 3;         // 2 x 4 wave grid

  // bijective XCD swizzle (m204)
  const int nwg = gridDim.x, orig = blockIdx.x;
  const int q = nwg >> 3, r = nwg & 7;
  const int xcd = orig & 7, jj = orig >> 3;
  const int wgid = (xcd < r ? xcd * (q + 1) : r * (q + 1) + (xcd - r) * q) + jj;
  const int tm = wgid % gm, tn = wgid / gm;
  const int row0 = tm * 256, col0 = tn * 256;

  // ---- staging source (inverse swizzle).  Per issue of 512 lanes:
  // pair-row pr = i*64 + tid>>3, dest pair-byte prb = (tid&7)*16,
  // logical rb = prb ^ ((pr&7)<<4); row = 2*pr + (rb>>6); colbyte = rb&63.
  const int pr8 = tid >> 3;                                  // 0..63
  const int rb  = (((tid & 7) ^ (pr8 & 7)) << 4);            // 0..112
  const int sr0 = (pr8 << 1) | (rb >> 6);                    // 0..127
  const int scol = (rb & 63) >> 1;                           // 0,8,16,24 els
  const int ar0 = imin(row0 + sr0, M - 1);
  const int ar1 = imin(row0 + 128 + sr0, M - 1);
  const u16* aS0 = A + (size_t)ar0 * K + scol;
  const u16* aS1 = A + (size_t)ar1 * K + scol;
  const u16* bS0 = B + (size_t)(col0 + sr0) * K + scol;
  const u16* bS1 = B + (size_t)(col0 + 128 + sr0) * K + scol;
  u16* ldsA = lds;                 // 3 bufs x 8192 u16
  u16* ldsB = lds + 24576;
  const int wOff = w * 512;

  auto stage = [&](int b, int kt) {
    const int k0 = kt << 5;
    gload_lds16(aS0 + k0, ldsA + b * 8192 + wOff);
    gload_lds16(aS1 + k0, ldsA + b * 8192 + 4096 + wOff);
    gload_lds16(bS0 + k0, ldsB + b * 8192 + wOff);
    gload_lds16(bS1 + k0, ldsB + b * 8192 + 4096 + wOff);
  };

  // ---- swizzled read base (u16 elements).  Logical (row r, kbyte hi*16):
  // pair = r>>1, pb = ((r&1)<<6)|(hi<<4), swz addr = pair*128 + (pb ^ ((pair&7)<<4))
  const int ax = (((lo & 1) << 5) | (hi << 3)) ^ ((lo >> 1) << 3);
  const u16* aR = ldsA + (wm * 64 + (lo >> 1)) * 64 + ax;
  const u16* bR = ldsB + (wn * 32 + (lo >> 1)) * 64 + ax;

  f32x4 acc[8][4];
  const f32x4 z = {0.f, 0.f, 0.f, 0.f};
  #pragma unroll
  for (int m = 0; m < 8; m++)
    #pragma unroll
    for (int n = 0; n < 4; n++) acc[m][n] = z;

  auto compute = [&](int b) {
    const u16* ap = aR + b * 8192;
    const u16* bp = bR + b * 8192;
    bf16x8 af[8], bv[4];
    #pragma unroll
    for (int n = 0; n < 4; n++)
      bv[n] = __builtin_bit_cast(bf16x8, *(const u32x4*)(bp + n * 512));
    #pragma unroll
    for (int m = 0; m < 8; m++)
      af[m] = __builtin_bit_cast(bf16x8, *(const u32x4*)(ap + m * 512));
    #pragma unroll
    for (int m = 0; m < 8; m++)
      #pragma unroll
      for (int n = 0; n < 4; n++)
        acc[m][n] = __builtin_amdgcn_mfma_f32_16x16x32_bf16(af[m], bv[n], acc[m][n], 0, 0, 0);
  };

  const int NT = K >> 5;
  // prologue: tiles 0,1 in flight; wait for tile 0 (leave tile 1's 4 loads)
  stage(0, 0);
  stage(1, 1);
  asm volatile("s_waitcnt vmcnt(4)" ::: "memory");
  __builtin_amdgcn_s_barrier();
  asm volatile("" ::: "memory");

  int bcur = 0, bnx2 = 2;
  for (int t = 0; t < NT - 2; ++t) {
    stage(bnx2, t + 2);                       // writes buf consumed at t-1
    compute(bcur);
    asm volatile("s_waitcnt vmcnt(4)" ::: "memory");  // tile t+1 landed
    __builtin_amdgcn_s_barrier();
    asm volatile("" ::: "memory");
    bcur = (bcur == 2) ? 0 : bcur + 1;
    bnx2 = (bnx2 == 2) ? 0 : bnx2 + 1;
  }
  // t = NT-2 (nothing left to stage; drain for last tile)
  compute(bcur);
  asm volatile("s_waitcnt vmcnt(0)" ::: "memory");
  __builtin_amdgcn_s_barrier();
  asm volatile("" ::: "memory");
  bcur = (bcur == 2) ? 0 : bcur + 1;
  // t = NT-1
  compute(bcur);

  // ---- epilogue
  const int rbase = row0 + wm * 128, cbase = col0 + wn * 64;
  #pragma unroll
  for (int n = 0; n < 4; n++) {
    int colc = cbase + n * 16 + lo;
    float bvv = bias[colc];
    #pragma unroll
    for (int m = 0; m < 8; m++) {
      int rr0 = rbase + m * 16 + hi * 4;
      #pragma unroll
      for (int j = 0; j < 4; j++) {
        int rr = rr0 + j;
        if (rr >= M) continue;
        float v = acc[m][n][j] + bvv;
        if constexpr (EPI == EPI_BF16) {
          outB[(size_t)rr * N + colc] = f2bf(v);
        } else if constexpr (EPI == EPI_GELU) {
          float gv = v / (1.f + __expf(-1.702f * v));
          outB[(size_t)rr * N + colc] = f2bf(gv);
        } else if constexpr (EPI == EPI_RES) {
          float sres = resid[(size_t)rr * N + colc] + v;
          outF[(size_t)rr * N + colc] = sres;
          outB[(size_t)rr * N + colc] = f2bf(sres);
        } else if constexpr (EPI == EPI_ACC) {
          outF[(size_t)rr * N + colc] += v;
        } else { // EPI_ACC_SKIPCLS
          int rm = (rr >> 8) * 257 + (rr & 255) + 1;
          outF[(size_t)rm * N + colc] += v;
        }
      }
    }
  }
}

// ---------------------------------------------------------------------------
// Fused attention (unchanged from round 1).
// ---------------------------------------------------------------------------
__global__ __launch_bounds__(256) void attn_kernel(
    const u16* __restrict__ qkv, u16* __restrict__ out)
{
  __shared__ u16 Vt[64 * 296];
  __shared__ u16 Ps[4][16 * 136];
  const int bt = blockIdx.x >> 4;
  const int h  = blockIdx.x & 15;
  const int t  = threadIdx.x, l = t & 63, w = t >> 6;
  const int lo = l & 15, hi = l >> 4;
  const size_t base = (size_t)bt * 257 * 3072 + (size_t)h * 64;

  for (int ch = t; ch < 257 * 8; ch += 256) {
    int r = ch >> 3, s8 = ch & 7;
    u32x4 v = *(const u32x4*)(qkv + base + (size_t)r * 3072 + 2048 + s8 * 8);
    union { u32x4 v4; u16 us[8]; } cv; cv.v4 = v;
    #pragma unroll
    for (int i = 0; i < 8; i++) Vt[(s8 * 8 + i) * 296 + r] = cv.us[i];
  }
  for (int ch = t; ch < 64 * 39; ch += 256)
    Vt[(ch / 39) * 296 + 257 + (ch % 39)] = 0;
  __syncthreads();

  for (int c = w; c < 17; c += 4) {
    int qr = c * 16 + lo; qr = (qr < 257) ? qr : 256;
    const u16* qp = qkv + base + (size_t)qr * 3072 + hi * 8;
    bf16x8 q0 = __builtin_bit_cast(bf16x8, *(const u32x4*)qp);
    bf16x8 q1 = __builtin_bit_cast(bf16x8, *(const u32x4*)(qp + 32));

    f32x4 s[17];
    #pragma unroll
    for (int tt = 0; tt < 17; tt++) {
      int kr = tt * 16 + lo; kr = (kr < 257) ? kr : 256;
      const u16* kp = qkv + base + (size_t)kr * 3072 + 1024 + hi * 8;
      bf16x8 k0 = __builtin_bit_cast(bf16x8, *(const u32x4*)kp);
      bf16x8 k1 = __builtin_bit_cast(bf16x8, *(const u32x4*)(kp + 32));
      f32x4 a = {0.f, 0.f, 0.f, 0.f};
      a = __builtin_amdgcn_mfma_f32_16x16x32_bf16(q0, k0, a, 0, 0, 0);
      a = __builtin_amdgcn_mfma_f32_16x16x32_bf16(q1, k1, a, 0, 0, 0);
      s[tt] = a;
    }
    float mx[4] = {-1e30f, -1e30f, -1e30f, -1e30f};
    #pragma unroll
    for (int tt = 0; tt < 17; tt++) {
      int key = tt * 16 + lo;
      #pragma unroll
      for (int j = 0; j < 4; j++) {
        float v = s[tt][j] * 0.125f;
        v = (key < 257) ? v : -1e30f;
        s[tt][j] = v;
        mx[j] = fmaxf(mx[j], v);
      }
    }
    #pragma unroll
    for (int j = 0; j < 4; j++)
      #pragma unroll
      for (int msk = 1; msk < 16; msk <<= 1) mx[j] = fmaxf(mx[j], __shfl_xor(mx[j], msk));
    float sm[4] = {0.f, 0.f, 0.f, 0.f};
    #pragma unroll
    for (int tt = 0; tt < 17; tt++)
      #pragma unroll
      for (int j = 0; j < 4; j++) {
        float p = __expf(s[tt][j] - mx[j]);
        s[tt][j] = p; sm[j] += p;
      }
    #pragma unroll
    for (int j = 0; j < 4; j++) {
      #pragma unroll
      for (int msk = 1; msk < 16; msk <<= 1) sm[j] += __shfl_xor(sm[j], msk);
      sm[j] = 1.f / sm[j];
    }

    u16* P = &Ps[w][0];
    f32x4 o[4];
    #pragma unroll
    for (int n = 0; n < 4; n++) o[n] = (f32x4){0.f, 0.f, 0.f, 0.f};
    #pragma unroll
    for (int ph = 0; ph < 3; ph++) {
      const int TT = (ph < 2) ? 8 : 1;
      #pragma unroll
      for (int ti = 0; ti < TT; ti++) {
        int tt = ph * 8 + ti;
        #pragma unroll
        for (int j = 0; j < 4; j++)
          P[(hi * 4 + j) * 136 + ti * 16 + lo] = f2bf(s[tt][j] * sm[j]);
      }
      if (ph == 2) {
        #pragma unroll
        for (int j = 0; j < 4; j++) P[(hi * 4 + j) * 136 + 16 + lo] = 0;
      }
      const int NKS = (ph < 2) ? 4 : 1;
      #pragma unroll
      for (int ks = 0; ks < NKS; ks++) {
        bf16x8 af = __builtin_bit_cast(bf16x8,
          *(const u32x4*)&P[lo * 136 + ks * 32 + hi * 8]);
        #pragma unroll
        for (int n = 0; n < 4; n++) {
          bf16x8 bfr = __builtin_bit_cast(bf16x8,
            *(const u32x4*)&Vt[(n * 16 + lo) * 296 + ph * 128 + ks * 32 + hi * 8]);
          o[n] = __builtin_amdgcn_mfma_f32_16x16x32_bf16(af, bfr, o[n], 0, 0, 0);
        }
      }
    }
    #pragma unroll
    for (int n = 0; n < 4; n++)
      #pragma unroll
      for (int j = 0; j < 4; j++) {
        int row = c * 16 + hi * 4 + j;
        if (row < 257)
          out[(size_t)(bt * 257 + row) * 1024 + h * 64 + n * 16 + lo] = f2bf(o[n][j]);
      }
  }
}

// ---------------------------------------------------------------------------
// launch
// ---------------------------------------------------------------------------
extern "C" void kernel_launch(void* const* d_in, const int* in_sizes, int n_in,
                              void* d_out, int out_size, void* d_ws, size_t ws_size,
                              hipStream_t stream)
{
  const float* x       = (const float*)d_in[0];
  const float* ln1_g   = (const float*)d_in[1];
  const float* ln1_b   = (const float*)d_in[2];
  const float* w_in    = (const float*)d_in[3];
  const float* b_in    = (const float*)d_in[4];
  const float* w_out   = (const float*)d_in[5];
  const float* b_out   = (const float*)d_in[6];
  const float* o_fc1_w = (const float*)d_in[7];
  const float* o_fc1_b = (const float*)d_in[8];
  const float* o_conv_w= (const float*)d_in[9];
  const float* o_conv_b= (const float*)d_in[10];
  const float* o_fc2_w = (const float*)d_in[11];
  const float* o_fc2_b = (const float*)d_in[12];
  const float* a_fc1_w = (const float*)d_in[13];
  const float* a_fc1_b = (const float*)d_in[14];
  const float* a_conv_w= (const float*)d_in[15];
  const float* a_conv_b= (const float*)d_in[16];
  const float* a_fc2_w = (const float*)d_in[17];
  const float* a_fc2_b = (const float*)d_in[18];
  const float* ln2_g   = (const float*)d_in[19];
  const float* ln2_b   = (const float*)d_in[20];
  const float* mfc_w   = (const float*)d_in[21];
  const float* mfc_b   = (const float*)d_in[22];
  const float* mproj_w = (const float*)d_in[23];
  const float* mproj_b = (const float*)d_in[24];
  float* xo = (float*)d_out;

  char* ws = (char*)d_ws;
  u16* WB = (u16*)ws;                                     // bf16 weights
  u16* R0 = (u16*)(ws + 28311552);                        // 16448x1024 bf16
  u16* R1 = (u16*)(ws + 28311552 + 33685504);             // 16448x3072 bf16
  u16* R2 = (u16*)(ws + 28311552 + 33685504 + 101056512); // 16448x1024 bf16
  u16* w_in_bf  = WB + 0;
  u16* w_out_bf = WB + 3145728;
  u16* ofc1_bf  = WB + 4194304;
  u16* ofc2_bf  = WB + 4587520;
  u16* afc1_bf  = WB + 4980736;
  u16* afc2_bf  = WB + 5373952;
  u16* mfc_bf   = WB + 5767168;
  u16* mproj_bf = WB + 9961472;
  u16* off1 = R1;                       // 16384x384
  u16* offc = R1 + 6291456;             // 16384x384
  u16* y1   = R1 + 12582912;            // 16448x384
  u16* yc   = R1 + 12582912 + 6316032;  // 16448x384

  cvt_weights<<<13824, 256, 0, stream>>>(w_in, w_out, o_fc1_w, o_fc2_w,
                                         a_fc1_w, a_fc2_w, mfc_w, mproj_w, WB);
  ln_bf16<<<16448, 256, 0, stream>>>(x, ln1_g, ln1_b, R0);
  gemm256<EPI_BF16><<<65 * 12, 512, 0, stream>>>(
      R0, w_in_bf, b_in, nullptr, R1, nullptr, 16448, 3072, 1024, 65);
  attn_kernel<<<1024, 256, 0, stream>>>(R1, R2);
  gemm256<EPI_RES><<<65 * 4, 512, 0, stream>>>(
      R2, w_out_bf, b_out, xo, R0, x, 16448, 1024, 1024, 65);
  diff_bf16<<<16384, 256, 0, stream>>>(xo, R2);
  gemm_bt<EPI_BF16><<<dim3(128, 3), 256, 0, stream>>>(
      R2, ofc1_bf, o_fc1_b, nullptr, off1, nullptr, 16384, 384, 1024);
  dwconv3x3<<<24576, 256, 0, stream>>>(off1, o_conv_w, o_conv_b, offc);
  gemm256<EPI_ACC_SKIPCLS><<<64 * 4, 512, 0, stream>>>(
      offc, ofc2_bf, o_fc2_b, xo, nullptr, nullptr, 16384, 1024, 384, 64);
  gemm_bt<EPI_BF16><<<dim3(129, 3), 256, 0, stream>>>(
      R0, afc1_bf, a_fc1_b, nullptr, y1, nullptr, 16448, 384, 1024);
  dwconv1d<<<24672, 256, 0, stream>>>(y1, a_conv_w, a_conv_b, yc);
  gemm256<EPI_ACC><<<65 * 4, 512, 0, stream>>>(
      yc, afc2_bf, a_fc2_b, xo, nullptr, nullptr, 16448, 1024, 384, 65);
  ln_bf16<<<16448, 256, 0, stream>>>(xo, ln2_g, ln2_b, R0);
  gemm256<EPI_GELU><<<65 * 16, 512, 0, stream>>>(
      R0, mfc_bf, mfc_b, nullptr, R1, nullptr, 16448, 4096, 1024, 65);
  gemm256<EPI_ACC><<<65 * 4, 512, 0, stream>>>(
      R1, mproj_bf, mproj_b, xo, nullptr, nullptr, 16448, 1024, 4096, 65);
}

// Round 3
// 1472.907 us; speedup vs baseline: 1.1410x; 1.0072x over previous
//
#include <hip/hip_runtime.h>
#include <cstdint>
#include <cstddef>

// ---------------------------------------------------------------------------
// ResidualAttentionBlock_adapter — MI355X (gfx950)  — round 3
// gemm256 rewritten as a 4-phase-per-K-tile interleaved schedule (T3+T4+T5):
// BK=64, 128KB double-buffered LDS, per-phase {ds_read quad | stage 1/4 tile |
// barrier | setprio MFMA x16 | barrier}, one counted vmcnt drain per K-tile,
// XOR-swizzled LDS (inverse-swizzle on gload source), supergroup-of-4-columns
// tile order + bijective XCD chunking for L2-resident staging.
// ---------------------------------------------------------------------------

typedef unsigned short u16;
typedef __attribute__((ext_vector_type(4))) float  f32x4;
typedef __attribute__((ext_vector_type(8))) short  bf16x8;
typedef __attribute__((ext_vector_type(4))) unsigned int u32x4;

#define AS1 __attribute__((address_space(1)))
#define AS3 __attribute__((address_space(3)))

__device__ __forceinline__ float bf2f(u16 u) {
  unsigned int x = ((unsigned int)u) << 16;
  return __builtin_bit_cast(float, x);
}
__device__ __forceinline__ u16 f2bf(float f) {
  unsigned int x = __builtin_bit_cast(unsigned int, f);
  x = x + 0x7fffu + ((x >> 16) & 1u);   // round-to-nearest-even
  return (u16)(x >> 16);
}
__device__ __forceinline__ unsigned int pack2(float a, float b) {
  return (unsigned int)f2bf(a) | ((unsigned int)f2bf(b) << 16);
}
__device__ __forceinline__ int imin(int a, int b) { return a < b ? a : b; }

// async global->LDS, 16B per lane. LDS dest is wave-uniform base + lane*16.
__device__ __forceinline__ void gload_lds16(const void* g, void* l) {
  __builtin_amdgcn_global_load_lds((const AS1 unsigned int*)g,
                                   (AS3 unsigned int*)l, 16, 0, 0);
}

// ---------------------------------------------------------------------------
// Weight fp32 -> bf16 conversion (all 8 matrices in one kernel).
// ---------------------------------------------------------------------------
__global__ __launch_bounds__(256) void cvt_weights(
    const float* __restrict__ w_in, const float* __restrict__ w_out,
    const float* __restrict__ ofc1, const float* __restrict__ ofc2,
    const float* __restrict__ afc1, const float* __restrict__ afc2,
    const float* __restrict__ mfc,  const float* __restrict__ mproj,
    u16* __restrict__ dst)
{
  long i4 = (long)blockIdx.x * 256 + threadIdx.x;   // 3,538,944 float4 units
  long e = i4 * 4;
  const float* src; long base;
  if      (e < 3145728L) { src = w_in;  base = 0L; }
  else if (e < 4194304L) { src = w_out; base = 3145728L; }
  else if (e < 4587520L) { src = ofc1;  base = 4194304L; }
  else if (e < 4980736L) { src = ofc2;  base = 4587520L; }
  else if (e < 5373952L) { src = afc1;  base = 4980736L; }
  else if (e < 5767168L) { src = afc2;  base = 5373952L; }
  else if (e < 9961472L) { src = mfc;   base = 5767168L; }
  else                   { src = mproj; base = 9961472L; }
  float4 v = *(const float4*)(src + (e - base));
  uint2 o; o.x = pack2(v.x, v.y); o.y = pack2(v.z, v.w);
  *(uint2*)(dst + e) = o;
}

// ---------------------------------------------------------------------------
// Fused LayerNorm (D=1024) -> bf16.  One block (256 thr) per row.
// ---------------------------------------------------------------------------
__global__ __launch_bounds__(256) void ln_bf16(
    const float* __restrict__ x, const float* __restrict__ g,
    const float* __restrict__ b, u16* __restrict__ out)
{
  int row = blockIdx.x;
  const float4* xr = (const float4*)(x + (size_t)row * 1024);
  float4 v = xr[threadIdx.x];
  float s = v.x + v.y + v.z + v.w;
  float q = v.x * v.x + v.y * v.y + v.z * v.z + v.w * v.w;
  #pragma unroll
  for (int m = 1; m < 64; m <<= 1) { s += __shfl_xor(s, m); q += __shfl_xor(q, m); }
  __shared__ float ss[4], qq[4];
  if ((threadIdx.x & 63) == 0) { ss[threadIdx.x >> 6] = s; qq[threadIdx.x >> 6] = q; }
  __syncthreads();
  s = ss[0] + ss[1] + ss[2] + ss[3];
  q = qq[0] + qq[1] + qq[2] + qq[3];
  float mu = s * (1.f / 1024.f);
  float var = q * (1.f / 1024.f) - mu * mu;
  float rs = rsqrtf(var + 1e-5f);
  float4 gg = ((const float4*)g)[threadIdx.x];
  float4 bb = ((const float4*)b)[threadIdx.x];
  float o0 = (v.x - mu) * rs * gg.x + bb.x;
  float o1 = (v.y - mu) * rs * gg.y + bb.y;
  float o2 = (v.z - mu) * rs * gg.z + bb.z;
  float o3 = (v.w - mu) * rs * gg.w + bb.w;
  uint2 o; o.x = pack2(o0, o1); o.y = pack2(o2, o3);
  *(uint2*)(out + (size_t)row * 1024 + threadIdx.x * 4) = o;
}

// ---------------------------------------------------------------------------
// Temporal diff -> bf16, 16384 rows x 1024.
// ---------------------------------------------------------------------------
__global__ __launch_bounds__(256) void diff_bf16(
    const float* __restrict__ x1, u16* __restrict__ out)
{
  int i = blockIdx.x * 256 + threadIdx.x;   // 4,194,304 units
  int r = i >> 8;                           // 0..16383
  int c4 = i & 255;
  int f = r >> 8;                           // frame 0..63
  int p = r & 255;
  int t = f & 15;
  int rowA = f * 257 + 1 + p;
  int rowB = (t == 0) ? rowA : (f - 1) * 257 + 1 + p;
  float4 a = ((const float4*)(x1 + (size_t)rowA * 1024))[c4];
  float4 b = ((const float4*)(x1 + (size_t)rowB * 1024))[c4];
  uint2 o; o.x = pack2(a.x - b.x, a.y - b.y); o.y = pack2(a.z - b.z, a.w - b.w);
  *(uint2*)(out + (size_t)r * 1024 + c4 * 4) = o;
}

// ---------------------------------------------------------------------------
// Depthwise 3x3 spatial conv (per frame, zero pad).  [64][16][16][384]
// ---------------------------------------------------------------------------
__global__ __launch_bounds__(256) void dwconv3x3(
    const u16* __restrict__ in, const float* __restrict__ w,
    const float* __restrict__ bias, u16* __restrict__ out)
{
  int idx = blockIdx.x * 256 + threadIdx.x;  // 6,291,456
  int c = idx % 384;
  int pos = idx / 384;
  int xx = pos & 15, yy = (pos >> 4) & 15, f = pos >> 8;
  float acc = bias[c];
  #pragma unroll
  for (int kh = 0; kh < 3; kh++) {
    int y2 = yy + kh - 1;
    if (y2 < 0 || y2 > 15) continue;
    #pragma unroll
    for (int kw = 0; kw < 3; kw++) {
      int x2 = xx + kw - 1;
      if (x2 < 0 || x2 > 15) continue;
      acc += bf2f(in[((size_t)(f * 256 + y2 * 16 + x2)) * 384 + c]) * w[(kh * 3 + kw) * 384 + c];
    }
  }
  out[(size_t)idx] = f2bf(acc);
}

// ---------------------------------------------------------------------------
// Depthwise temporal conv1d (kernel 3, zero pad).  [64*257][384]
// ---------------------------------------------------------------------------
__global__ __launch_bounds__(256) void dwconv1d(
    const u16* __restrict__ in, const float* __restrict__ w,
    const float* __restrict__ bias, u16* __restrict__ out)
{
  int idx = blockIdx.x * 256 + threadIdx.x;  // 6,316,032
  int c = idx % 384;
  int rl = idx / 384;
  int bt = rl / 257, l = rl % 257;
  int bv = bt >> 4, t = bt & 15;
  float acc = bias[c];
  #pragma unroll
  for (int dt = 0; dt < 3; dt++) {
    int tt = t + dt - 1;
    if (tt < 0 || tt > 15) continue;
    acc += bf2f(in[((size_t)((bv * 16 + tt) * 257 + l)) * 384 + c]) * w[dt * 384 + c];
  }
  out[(size_t)idx] = f2bf(acc);
}

enum { EPI_BF16 = 0, EPI_GELU = 1, EPI_RES = 2, EPI_ACC = 3, EPI_ACC_SKIPCLS = 4 };

// ---------------------------------------------------------------------------
// 128x128 m97-style GEMM (kept for N=384 GEMMs).
// ---------------------------------------------------------------------------
template <int EPI>
__global__ __launch_bounds__(256) void gemm_bt(
    const u16* __restrict__ A, const u16* __restrict__ B,
    const float* __restrict__ bias,
    float* __restrict__ outF, u16* __restrict__ outB,
    const float* __restrict__ resid,
    int M, int N, int K)
{
  __shared__ u16 As[128 * 64];
  __shared__ u16 Bs[128 * 64];
  const int t = threadIdx.x, l = t & 63, w = t >> 6;
  const int row0 = blockIdx.x * 128, col0 = blockIdx.y * 128;
  const int wr = w >> 1, wc = w & 1;
  const int lo = l & 15, hi = l >> 4;
  const int larow = l >> 3, lacol = (l & 7) * 8;

  f32x4 acc[4][4];
  const f32x4 z = {0.f, 0.f, 0.f, 0.f};
  #pragma unroll
  for (int m = 0; m < 4; m++)
    #pragma unroll
    for (int n = 0; n < 4; n++) acc[m][n] = z;

  for (int k0 = 0; k0 < K; k0 += 64) {
    #pragma unroll
    for (int i = 0; i < 4; i++) {
      int rr = i * 32 + w * 8 + larow;
      int ra = row0 + rr; ra = (ra < M) ? ra : (M - 1);
      gload_lds16(A + (size_t)ra * K + k0 + lacol, As + i * 2048 + w * 512);
      gload_lds16(B + (size_t)(col0 + rr) * K + k0 + lacol, Bs + i * 2048 + w * 512);
    }
    __syncthreads();
    #pragma unroll
    for (int kk = 0; kk < 2; kk++) {
      bf16x8 af[4], bfr[4];
      #pragma unroll
      for (int m = 0; m < 4; m++)
        af[m] = __builtin_bit_cast(bf16x8,
          *(const u32x4*)&As[(wr * 64 + m * 16 + lo) * 64 + kk * 32 + hi * 8]);
      #pragma unroll
      for (int n = 0; n < 4; n++)
        bfr[n] = __builtin_bit_cast(bf16x8,
          *(const u32x4*)&Bs[(wc * 64 + n * 16 + lo) * 64 + kk * 32 + hi * 8]);
      #pragma unroll
      for (int m = 0; m < 4; m++)
        #pragma unroll
        for (int n = 0; n < 4; n++)
          acc[m][n] = __builtin_amdgcn_mfma_f32_16x16x32_bf16(af[m], bfr[n], acc[m][n], 0, 0, 0);
    }
    __syncthreads();
  }

  const int rbase = row0 + wr * 64, cbase = col0 + wc * 64;
  #pragma unroll
  for (int n = 0; n < 4; n++) {
    int colc = cbase + n * 16 + lo;
    float bv = bias[colc];
    #pragma unroll
    for (int m = 0; m < 4; m++) {
      int rr0 = rbase + m * 16 + hi * 4;
      #pragma unroll
      for (int j = 0; j < 4; j++) {
        int r = rr0 + j;
        if (r >= M) continue;
        float v = acc[m][n][j] + bv;
        if constexpr (EPI == EPI_BF16) {
          outB[(size_t)r * N + colc] = f2bf(v);
        } else if constexpr (EPI == EPI_GELU) {
          float gv = v / (1.f + __expf(-1.702f * v));
          outB[(size_t)r * N + colc] = f2bf(gv);
        } else if constexpr (EPI == EPI_RES) {
          float sres = resid[(size_t)r * N + colc] + v;
          outF[(size_t)r * N + colc] = sres;
          outB[(size_t)r * N + colc] = f2bf(sres);
        } else if constexpr (EPI == EPI_ACC) {
          outF[(size_t)r * N + colc] += v;
        } else {
          int rm = (r >> 8) * 257 + (r & 255) + 1;
          outF[(size_t)rm * N + colc] += v;
        }
      }
    }
  }
}

// ---------------------------------------------------------------------------
// 256x256 GEMM, BK=64, 8 waves (2x4), 128KB dbuf LDS, 4-phase interleave.
// Phase = {ds_read quadrant frags | stage 1/4 next tile | bar | setprio
// MFMA x16 | bar}.  One vmcnt(0) per K-tile (>=2-phase latency cover).
// XOR swizzle: LDS[row][colb] = G[row][colb ^ ((row&7)<<4)] (byte units).
// Requires: N % 256 == 0, K % 64 == 0.  Grid = gm * gn, gn % 4 == 0.
// ---------------------------------------------------------------------------
template <int EPI>
__global__ __launch_bounds__(512, 2) void gemm256(
    const u16* __restrict__ A, const u16* __restrict__ B,
    const float* __restrict__ bias,
    float* __restrict__ outF, u16* __restrict__ outB,
    const float* __restrict__ resid,
    int M, int N, int K, int gm)
{
  __shared__ u16 lds[65536];                 // 128 KB: buf c at c*32768 (A), +16384 (B)
  const int tid = threadIdx.x;
  const int w = tid >> 6, lane = tid & 63;
  const int lo = lane & 15, hi = lane >> 4;
  const int wm = w >> 2, wn = w & 3;         // 2 x 4 wave grid

  // bijective XCD chunking (m204), then supergroup-of-4-columns order
  const int nwg = gridDim.x, orig = blockIdx.x;
  const int q = nwg >> 3, r = nwg & 7;
  const int xcd = orig & 7, jj = orig >> 3;
  const int lid = (xcd < r ? xcd * (q + 1) : r * (q + 1) + (xcd - r) * q) + jj;
  const int sg = lid / (gm * 4), rem = lid - sg * (gm * 4);
  const int tm = rem >> 2, tn = sg * 4 + (rem & 3);
  const int row0 = tm * 256, col0 = tn * 256;

  // ---- staging (inverse swizzle on global source; LDS dest linear)
  const int srow = w * 8 + (lane >> 3);               // + i*64
  const int scolEl = ((lane & 7) ^ (lane >> 3)) << 3; // element offset
  const u16* aS[4]; const u16* bS[4];
  #pragma unroll
  for (int i = 0; i < 4; i++) {
    int ar = imin(row0 + i * 64 + srow, M - 1);
    aS[i] = A + (size_t)ar * K + scolEl;
    bS[i] = B + (size_t)(col0 + i * 64 + srow) * K + scolEl;
  }
  auto stageA = [&](int c2, int kOff) {
    u16* d = (u16*)lds + c2 * 32768 + (w << 9);
    #pragma unroll
    for (int i = 0; i < 4; i++) gload_lds16(aS[i] + kOff, d + i * 4096);
  };
  auto stageB = [&](int c2, int kOff) {
    u16* d = (u16*)lds + c2 * 32768 + 16384 + (w << 9);
    #pragma unroll
    for (int i = 0; i < 4; i++) gload_lds16(bS[i] + kOff, d + i * 4096);
  };

  // ---- swizzled ds_read addressing (element units)
  const int swz = (lo & 7) << 3;
  const int cK0 = (hi << 3) ^ swz;           // kk=0
  const int cK1 = ((hi << 3) | 32) ^ swz;    // kk=1
  const int aRowE = (wm * 128 + lo) * 64;    // + m*1024
  const int bRowE = (wn * 64 + lo) * 64;     // + n*1024

  f32x4 acc[8][4];
  const f32x4 z = {0.f, 0.f, 0.f, 0.f};
  #pragma unroll
  for (int m = 0; m < 8; m++)
    #pragma unroll
    for (int n = 0; n < 4; n++) acc[m][n] = z;

  bf16x8 aF[4][2], bF0[2][2], bF1[2][2];

#define LOADA(BA, MH)                                                          \
  { _Pragma("unroll")                                                          \
    for (int mi = 0; mi < 4; mi++) {                                           \
      const u16* p = (BA) + aRowE + ((MH) * 4 + mi) * 1024;                    \
      aF[mi][0] = __builtin_bit_cast(bf16x8, *(const u32x4*)(p + cK0));        \
      aF[mi][1] = __builtin_bit_cast(bf16x8, *(const u32x4*)(p + cK1));        \
    } }
#define LOADB(BB, BF, NH)                                                      \
  { _Pragma("unroll")                                                          \
    for (int ni = 0; ni < 2; ni++) {                                           \
      const u16* p = (BB) + bRowE + ((NH) * 2 + ni) * 1024;                    \
      BF[ni][0] = __builtin_bit_cast(bf16x8, *(const u32x4*)(p + cK0));        \
      BF[ni][1] = __builtin_bit_cast(bf16x8, *(const u32x4*)(p + cK1));        \
    } }
#define MFMA16(MH, NH, BF)                                                     \
  { _Pragma("unroll")                                                          \
    for (int mi = 0; mi < 4; mi++)                                             \
      _Pragma("unroll")                                                        \
      for (int ni = 0; ni < 2; ni++)                                           \
        _Pragma("unroll")                                                      \
        for (int kk = 0; kk < 2; kk++)                                         \
          acc[(MH)*4+mi][(NH)*2+ni] = __builtin_amdgcn_mfma_f32_16x16x32_bf16( \
              aF[mi][kk], BF[ni][kk], acc[(MH)*4+mi][(NH)*2+ni], 0, 0, 0); }

  const int NT = K >> 6;
  // prologue: stage tile 0, drain, barrier
  stageA(0, 0);
  stageB(0, 0);
  asm volatile("s_waitcnt vmcnt(0)" ::: "memory");
  __builtin_amdgcn_s_barrier();

  for (int t = 0; t < NT; ++t) {
    const int c = t & 1;
    const u16* bufA = (const u16*)lds + c * 32768;
    const u16* bufB = bufA + 16384;
    const bool pf = (t + 1) < NT;
    const int kn = (t + 1) << 6;

    // ---- phase 0: quad (mh0, nh0); stage A(t+1)
    LOADA(bufA, 0);
    LOADB(bufB, bF0, 0);
    if (pf) stageA(c ^ 1, kn);
    __builtin_amdgcn_sched_barrier(0);
    __builtin_amdgcn_s_barrier();
    __builtin_amdgcn_s_setprio(1);
    MFMA16(0, 0, bF0);
    __builtin_amdgcn_s_setprio(0);
    __builtin_amdgcn_sched_barrier(0);
    __builtin_amdgcn_s_barrier();
    // ---- phase 1: quad (mh0, nh1); stage B(t+1)
    LOADB(bufB, bF1, 1);
    if (pf) stageB(c ^ 1, kn);
    __builtin_amdgcn_sched_barrier(0);
    __builtin_amdgcn_s_barrier();
    __builtin_amdgcn_s_setprio(1);
    MFMA16(0, 1, bF1);
    __builtin_amdgcn_s_setprio(0);
    __builtin_amdgcn_sched_barrier(0);
    __builtin_amdgcn_s_barrier();
    // ---- phase 2: quad (mh1, nh1)
    LOADA(bufA, 1);
    __builtin_amdgcn_sched_barrier(0);
    __builtin_amdgcn_s_barrier();
    __builtin_amdgcn_s_setprio(1);
    MFMA16(1, 1, bF1);
    __builtin_amdgcn_s_setprio(0);
    __builtin_amdgcn_sched_barrier(0);
    __builtin_amdgcn_s_barrier();
    // ---- phase 3: quad (mh1, nh0); drain staging, tile-end barrier
    __builtin_amdgcn_s_setprio(1);
    MFMA16(1, 0, bF0);
    __builtin_amdgcn_s_setprio(0);
    __builtin_amdgcn_sched_barrier(0);
    asm volatile("s_waitcnt vmcnt(0)" ::: "memory");
    __builtin_amdgcn_s_barrier();
  }
#undef LOADA
#undef LOADB
#undef MFMA16

  // ---- epilogue
  const int rbase = row0 + wm * 128, cbase = col0 + wn * 64;
  #pragma unroll
  for (int n = 0; n < 4; n++) {
    int colc = cbase + n * 16 + lo;
    float bvv = bias[colc];
    #pragma unroll
    for (int m = 0; m < 8; m++) {
      int rr0 = rbase + m * 16 + hi * 4;
      #pragma unroll
      for (int j = 0; j < 4; j++) {
        int rr = rr0 + j;
        if (rr >= M) continue;
        float v = acc[m][n][j] + bvv;
        if constexpr (EPI == EPI_BF16) {
          outB[(size_t)rr * N + colc] = f2bf(v);
        } else if constexpr (EPI == EPI_GELU) {
          float gv = v / (1.f + __expf(-1.702f * v));
          outB[(size_t)rr * N + colc] = f2bf(gv);
        } else if constexpr (EPI == EPI_RES) {
          float sres = resid[(size_t)rr * N + colc] + v;
          outF[(size_t)rr * N + colc] = sres;
          outB[(size_t)rr * N + colc] = f2bf(sres);
        } else if constexpr (EPI == EPI_ACC) {
          outF[(size_t)rr * N + colc] += v;
        } else { // EPI_ACC_SKIPCLS
          int rm = (rr >> 8) * 257 + (rr & 255) + 1;
          outF[(size_t)rm * N + colc] += v;
        }
      }
    }
  }
}

// ---------------------------------------------------------------------------
// Fused attention (unchanged).
// ---------------------------------------------------------------------------
__global__ __launch_bounds__(256) void attn_kernel(
    const u16* __restrict__ qkv, u16* __restrict__ out)
{
  __shared__ u16 Vt[64 * 296];
  __shared__ u16 Ps[4][16 * 136];
  const int bt = blockIdx.x >> 4;
  const int h  = blockIdx.x & 15;
  const int t  = threadIdx.x, l = t & 63, w = t >> 6;
  const int lo = l & 15, hi = l >> 4;
  const size_t base = (size_t)bt * 257 * 3072 + (size_t)h * 64;

  for (int ch = t; ch < 257 * 8; ch += 256) {
    int r = ch >> 3, s8 = ch & 7;
    u32x4 v = *(const u32x4*)(qkv + base + (size_t)r * 3072 + 2048 + s8 * 8);
    union { u32x4 v4; u16 us[8]; } cv; cv.v4 = v;
    #pragma unroll
    for (int i = 0; i < 8; i++) Vt[(s8 * 8 + i) * 296 + r] = cv.us[i];
  }
  for (int ch = t; ch < 64 * 39; ch += 256)
    Vt[(ch / 39) * 296 + 257 + (ch % 39)] = 0;
  __syncthreads();

  for (int c = w; c < 17; c += 4) {
    int qr = c * 16 + lo; qr = (qr < 257) ? qr : 256;
    const u16* qp = qkv + base + (size_t)qr * 3072 + hi * 8;
    bf16x8 q0 = __builtin_bit_cast(bf16x8, *(const u32x4*)qp);
    bf16x8 q1 = __builtin_bit_cast(bf16x8, *(const u32x4*)(qp + 32));

    f32x4 s[17];
    #pragma unroll
    for (int tt = 0; tt < 17; tt++) {
      int kr = tt * 16 + lo; kr = (kr < 257) ? kr : 256;
      const u16* kp = qkv + base + (size_t)kr * 3072 + 1024 + hi * 8;
      bf16x8 k0 = __builtin_bit_cast(bf16x8, *(const u32x4*)kp);
      bf16x8 k1 = __builtin_bit_cast(bf16x8, *(const u32x4*)(kp + 32));
      f32x4 a = {0.f, 0.f, 0.f, 0.f};
      a = __builtin_amdgcn_mfma_f32_16x16x32_bf16(q0, k0, a, 0, 0, 0);
      a = __builtin_amdgcn_mfma_f32_16x16x32_bf16(q1, k1, a, 0, 0, 0);
      s[tt] = a;
    }
    float mx[4] = {-1e30f, -1e30f, -1e30f, -1e30f};
    #pragma unroll
    for (int tt = 0; tt < 17; tt++) {
      int key = tt * 16 + lo;
      #pragma unroll
      for (int j = 0; j < 4; j++) {
        float v = s[tt][j] * 0.125f;
        v = (key < 257) ? v : -1e30f;
        s[tt][j] = v;
        mx[j] = fmaxf(mx[j], v);
      }
    }
    #pragma unroll
    for (int j = 0; j < 4; j++)
      #pragma unroll
      for (int msk = 1; msk < 16; msk <<= 1) mx[j] = fmaxf(mx[j], __shfl_xor(mx[j], msk));
    float sm[4] = {0.f, 0.f, 0.f, 0.f};
    #pragma unroll
    for (int tt = 0; tt < 17; tt++)
      #pragma unroll
      for (int j = 0; j < 4; j++) {
        float p = __expf(s[tt][j] - mx[j]);
        s[tt][j] = p; sm[j] += p;
      }
    #pragma unroll
    for (int j = 0; j < 4; j++) {
      #pragma unroll
      for (int msk = 1; msk < 16; msk <<= 1) sm[j] += __shfl_xor(sm[j], msk);
      sm[j] = 1.f / sm[j];
    }

    u16* P = &Ps[w][0];
    f32x4 o[4];
    #pragma unroll
    for (int n = 0; n < 4; n++) o[n] = (f32x4){0.f, 0.f, 0.f, 0.f};
    #pragma unroll
    for (int ph = 0; ph < 3; ph++) {
      const int TT = (ph < 2) ? 8 : 1;
      #pragma unroll
      for (int ti = 0; ti < TT; ti++) {
        int tt = ph * 8 + ti;
        #pragma unroll
        for (int j = 0; j < 4; j++)
          P[(hi * 4 + j) * 136 + ti * 16 + lo] = f2bf(s[tt][j] * sm[j]);
      }
      if (ph == 2) {
        #pragma unroll
        for (int j = 0; j < 4; j++) P[(hi * 4 + j) * 136 + 16 + lo] = 0;
      }
      const int NKS = (ph < 2) ? 4 : 1;
      #pragma unroll
      for (int ks = 0; ks < NKS; ks++) {
        bf16x8 af = __builtin_bit_cast(bf16x8,
          *(const u32x4*)&P[lo * 136 + ks * 32 + hi * 8]);
        #pragma unroll
        for (int n = 0; n < 4; n++) {
          bf16x8 bfr = __builtin_bit_cast(bf16x8,
            *(const u32x4*)&Vt[(n * 16 + lo) * 296 + ph * 128 + ks * 32 + hi * 8]);
          o[n] = __builtin_amdgcn_mfma_f32_16x16x32_bf16(af, bfr, o[n], 0, 0, 0);
        }
      }
    }
    #pragma unroll
    for (int n = 0; n < 4; n++)
      #pragma unroll
      for (int j = 0; j < 4; j++) {
        int row = c * 16 + hi * 4 + j;
        if (row < 257)
          out[(size_t)(bt * 257 + row) * 1024 + h * 64 + n * 16 + lo] = f2bf(o[n][j]);
      }
  }
}

// ---------------------------------------------------------------------------
// launch
// ---------------------------------------------------------------------------
extern "C" void kernel_launch(void* const* d_in, const int* in_sizes, int n_in,
                              void* d_out, int out_size, void* d_ws, size_t ws_size,
                              hipStream_t stream)
{
  const float* x       = (const float*)d_in[0];
  const float* ln1_g   = (const float*)d_in[1];
  const float* ln1_b   = (const float*)d_in[2];
  const float* w_in    = (const float*)d_in[3];
  const float* b_in    = (const float*)d_in[4];
  const float* w_out   = (const float*)d_in[5];
  const float* b_out   = (const float*)d_in[6];
  const float* o_fc1_w = (const float*)d_in[7];
  const float* o_fc1_b = (const float*)d_in[8];
  const float* o_conv_w= (const float*)d_in[9];
  const float* o_conv_b= (const float*)d_in[10];
  const float* o_fc2_w = (const float*)d_in[11];
  const float* o_fc2_b = (const float*)d_in[12];
  const float* a_fc1_w = (const float*)d_in[13];
  const float* a_fc1_b = (const float*)d_in[14];
  const float* a_conv_w= (const float*)d_in[15];
  const float* a_conv_b= (const float*)d_in[16];
  const float* a_fc2_w = (const float*)d_in[17];
  const float* a_fc2_b = (const float*)d_in[18];
  const float* ln2_g   = (const float*)d_in[19];
  const float* ln2_b   = (const float*)d_in[20];
  const float* mfc_w   = (const float*)d_in[21];
  const float* mfc_b   = (const float*)d_in[22];
  const float* mproj_w = (const float*)d_in[23];
  const float* mproj_b = (const float*)d_in[24];
  float* xo = (float*)d_out;

  char* ws = (char*)d_ws;
  u16* WB = (u16*)ws;                                     // bf16 weights
  u16* R0 = (u16*)(ws + 28311552);                        // 16448x1024 bf16
  u16* R1 = (u16*)(ws + 28311552 + 33685504);             // 16448x3072 bf16
  u16* R2 = (u16*)(ws + 28311552 + 33685504 + 101056512); // 16448x1024 bf16
  u16* w_in_bf  = WB + 0;
  u16* w_out_bf = WB + 3145728;
  u16* ofc1_bf  = WB + 4194304;
  u16* ofc2_bf  = WB + 4587520;
  u16* afc1_bf  = WB + 4980736;
  u16* afc2_bf  = WB + 5373952;
  u16* mfc_bf   = WB + 5767168;
  u16* mproj_bf = WB + 9961472;
  u16* off1 = R1;                       // 16384x384
  u16* offc = R1 + 6291456;             // 16384x384
  u16* y1   = R1 + 12582912;            // 16448x384
  u16* yc   = R1 + 12582912 + 6316032;  // 16448x384

  cvt_weights<<<13824, 256, 0, stream>>>(w_in, w_out, o_fc1_w, o_fc2_w,
                                         a_fc1_w, a_fc2_w, mfc_w, mproj_w, WB);
  ln_bf16<<<16448, 256, 0, stream>>>(x, ln1_g, ln1_b, R0);
  gemm256<EPI_BF16><<<65 * 12, 512, 0, stream>>>(
      R0, w_in_bf, b_in, nullptr, R1, nullptr, 16448, 3072, 1024, 65);
  attn_kernel<<<1024, 256, 0, stream>>>(R1, R2);
  gemm256<EPI_RES><<<65 * 4, 512, 0, stream>>>(
      R2, w_out_bf, b_out, xo, R0, x, 16448, 1024, 1024, 65);
  diff_bf16<<<16384, 256, 0, stream>>>(xo, R2);
  gemm_bt<EPI_BF16><<<dim3(128, 3), 256, 0, stream>>>(
      R2, ofc1_bf, o_fc1_b, nullptr, off1, nullptr, 16384, 384, 1024);
  dwconv3x3<<<24576, 256, 0, stream>>>(off1, o_conv_w, o_conv_b, offc);
  gemm256<EPI_ACC_SKIPCLS><<<64 * 4, 512, 0, stream>>>(
      offc, ofc2_bf, o_fc2_b, xo, nullptr, nullptr, 16384, 1024, 384, 64);
  gemm_bt<EPI_BF16><<<dim3(129, 3), 256, 0, stream>>>(
      R0, afc1_bf, a_fc1_b, nullptr, y1, nullptr, 16448, 384, 1024);
  dwconv1d<<<24672, 256, 0, stream>>>(y1, a_conv_w, a_conv_b, yc);
  gemm256<EPI_ACC><<<65 * 4, 512, 0, stream>>>(
      yc, afc2_bf, a_fc2_b, xo, nullptr, nullptr, 16448, 1024, 384, 65);
  ln_bf16<<<16448, 256, 0, stream>>>(xo, ln2_g, ln2_b, R0);
  gemm256<EPI_GELU><<<65 * 16, 512, 0, stream>>>(
      R0, mfc_bf, mfc_b, nullptr, R1, nullptr, 16448, 4096, 1024, 65);
  gemm256<EPI_ACC><<<65 * 4, 512, 0, stream>>>(
      R1, mproj_bf, mproj_b, xo, nullptr, nullptr, 16448, 1024, 4096, 65);
}